// Round 11
// baseline (120.227 us; speedup 1.0000x reference)
//
#include <hip/hip_runtime.h>
#include <hip/hip_bf16.h>
#include <math.h>

#define PIXELS 16384   // 4*64*64
#define C      128
#define KS     7
#define HEADS  4
#define HD     32      // head dim
#define QSCALE 0.17677669529663687f  // 32^-0.5

typedef __bf16 bf16x8 __attribute__((ext_vector_type(8)));
typedef __bf16 bf16x2 __attribute__((ext_vector_type(2)));
typedef float  f32x4  __attribute__((ext_vector_type(4)));
typedef float  f32x2  __attribute__((ext_vector_type(2)));

__device__ inline unsigned short f2bf(float f) {
    unsigned int u = __builtin_bit_cast(unsigned int, f);
    u += 0x7FFFu + ((u >> 16) & 1u);          // RNE
    return (unsigned short)(u >> 16);
}
__device__ inline float bflo(unsigned int u) {
    return __builtin_bit_cast(float, u << 16);
}
__device__ inline float bfhi(unsigned int u) {
    return __builtin_bit_cast(float, u & 0xFFFF0000u);
}

// ---------------------------------------------------------------------------
// prep (weights only): wT[448][128] = [qkv_w|g1_w]^T bf16;
// pT[128][128] = proj_w^T bf16; bias_ext[448].  grid 73 x 256.  (unchanged)
// ---------------------------------------------------------------------------
__global__ __launch_bounds__(256) void prep_kernel(
    const float* __restrict__ qkv_w, const float* __restrict__ g1_w,
    const float* __restrict__ qkv_b, const float* __restrict__ g1_b,
    const float* __restrict__ proj_w,
    unsigned short* __restrict__ wT, unsigned short* __restrict__ pT,
    float* __restrict__ bias_ext)
{
    const int blk = blockIdx.x, tid = threadIdx.x;
    if (blk < 56) {
        int n = blk * 8 + (tid >> 5);
        int kq = tid & 31;
        float f0, f1, f2, f3;
        if (n < 384) {
            f0 = qkv_w[(kq*4+0)*384 + n]; f1 = qkv_w[(kq*4+1)*384 + n];
            f2 = qkv_w[(kq*4+2)*384 + n]; f3 = qkv_w[(kq*4+3)*384 + n];
        } else {
            int nn = n - 384;
            f0 = g1_w[(kq*4+0)*64 + nn]; f1 = g1_w[(kq*4+1)*64 + nn];
            f2 = g1_w[(kq*4+2)*64 + nn]; f3 = g1_w[(kq*4+3)*64 + nn];
        }
        ushort4 o; o.x = f2bf(f0); o.y = f2bf(f1); o.z = f2bf(f2); o.w = f2bf(f3);
        *(ushort4*)(wT + n*128 + kq*4) = o;
    } else if (blk < 72) {
        int n = (blk - 56) * 8 + (tid >> 5);
        int kq = tid & 31;
        ushort4 o;
        o.x = f2bf(proj_w[(kq*4+0)*128 + n]);
        o.y = f2bf(proj_w[(kq*4+1)*128 + n]);
        o.z = f2bf(proj_w[(kq*4+2)*128 + n]);
        o.w = f2bf(proj_w[(kq*4+3)*128 + n]);
        *(ushort4*)(pT + n*128 + kq*4) = o;
    } else {
        for (int idx = tid; idx < 448; idx += 256)
            bias_ext[idx] = (idx < 384) ? qkv_b[idx] : g1_b[idx - 384];
    }
}

// ---------------------------------------------------------------------------
// GEMM 1 (fused): qkvb[pix][384] bf16 = bf16(x @ W + b), q cols scaled.
// BM=128 BN=64 K=128 (m93-style: 2x MFMA per staged byte vs BM=64; B-traffic
// halves).  A staged directly from fp32 x.  nt==6 block computes gate.
// grid (7, 128) x 256, LDS 48 KB -> 3 blocks/CU.
// ---------------------------------------------------------------------------
__global__ __launch_bounds__(256) void gemm_qkvh_fused(
    const float* __restrict__ x, const unsigned short* __restrict__ wT,
    const float* __restrict__ bias_ext, const float* __restrict__ g2_w,
    const float* __restrict__ g2_b, unsigned short* __restrict__ qkvb,
    float* __restrict__ gate)
{
    __shared__ __align__(16) unsigned short As[128*128];   // 32 KB
    __shared__ __align__(16) unsigned short Bs[64*128];    // 16 KB
    const int nt = blockIdx.x;
    const int n0 = nt * 64;
    const int m0 = blockIdx.y * 128;
    const int tid = threadIdx.x;

    // A: 128 rows x 16 chunks, fp32->bf16 during staging
#pragma unroll
    for (int it = 0; it < 8; it++) {
        int idx = tid + it*256, row = idx >> 4, c = idx & 15;
        const float* src = x + (size_t)(m0+row)*128 + c*8;
        float4 a = *(const float4*)src;
        float4 b2 = *(const float4*)(src + 4);
        uint4 v;
        v.x = (unsigned int)f2bf(a.x)  | ((unsigned int)f2bf(a.y)  << 16);
        v.y = (unsigned int)f2bf(a.z)  | ((unsigned int)f2bf(a.w)  << 16);
        v.z = (unsigned int)f2bf(b2.x) | ((unsigned int)f2bf(b2.y) << 16);
        v.w = (unsigned int)f2bf(b2.z) | ((unsigned int)f2bf(b2.w) << 16);
        *(uint4*)(As + row*128 + ((c ^ (row&7)) << 3)) = v;
    }
#pragma unroll
    for (int it = 0; it < 4; it++) {
        int idx = tid + it*256, row = idx >> 4, c = idx & 15;
        uint4 v = *(const uint4*)(wT + (size_t)(n0+row)*128 + c*8);
        *(uint4*)(Bs + row*128 + ((c ^ (row&7)) << 3)) = v;
    }
    __syncthreads();

    const int wave = tid >> 6, lane = tid & 63;
    const int l15 = lane & 15, quad = lane >> 4;
    const int wm = (wave & 1) * 64, wn = (wave >> 1) * 32;

    f32x4 acc[4][2] = {};
#pragma unroll
    for (int ks = 0; ks < 4; ks++) {
        bf16x8 af[4], bq[2];
#pragma unroll
        for (int mt = 0; mt < 4; mt++) {
            int m = wm + mt*16 + l15;
            af[mt] = *(const bf16x8*)(As + m*128 + (((ks*4+quad) ^ (m&7)) << 3));
        }
#pragma unroll
        for (int ntl = 0; ntl < 2; ntl++) {
            int n = wn + ntl*16 + l15;
            bq[ntl] = *(const bf16x8*)(Bs + n*128 + (((ks*4+quad) ^ (n&7)) << 3));
        }
#pragma unroll
        for (int mt = 0; mt < 4; mt++)
#pragma unroll
            for (int ntl = 0; ntl < 2; ntl++)
                acc[mt][ntl] = __builtin_amdgcn_mfma_f32_16x16x32_bf16(
                    af[mt], bq[ntl], acc[mt][ntl], 0, 0, 0);
    }
    __syncthreads();   // As/Bs dead; reuse below

    if (nt < 6) {
        unsigned short* Cs = (unsigned short*)As;   // 128x64 bf16 = 16 KB
#pragma unroll
        for (int ntl = 0; ntl < 2; ntl++) {
            int nl = wn + ntl*16 + l15;
            int ng = n0 + nl;
            float qs = (ng < 128) ? QSCALE : 1.0f;
            float bv = bias_ext[ng];
#pragma unroll
            for (int mt = 0; mt < 4; mt++)
#pragma unroll
                for (int r = 0; r < 4; r++) {
                    int ml = wm + mt*16 + quad*4 + r;
                    Cs[ml*64 + nl] = f2bf((acc[mt][ntl][r] + bv) * qs);
                }
        }
        __syncthreads();
        // 256 threads, 128 rows: 2 threads/row, each writes 32 hw (64 B)
        int row = tid >> 1, part = tid & 1;
        const unsigned short* srow = Cs + row*64 + part*32;
        unsigned short* dst = qkvb + (size_t)(m0+row)*384 + n0 + part*32;
        *(uint4*)(dst + 0)  = *(const uint4*)(srow + 0);
        *(uint4*)(dst + 8)  = *(const uint4*)(srow + 8);
        *(uint4*)(dst + 16) = *(const uint4*)(srow + 16);
        *(uint4*)(dst + 24) = *(const uint4*)(srow + 24);
    } else {
        float* gpart = (float*)Bs;   // [2][128] f32 = 1 KB
        float rs[4][4];
#pragma unroll
        for (int mt = 0; mt < 4; mt++)
#pragma unroll
            for (int r = 0; r < 4; r++) rs[mt][r] = 0.0f;
#pragma unroll
        for (int ntl = 0; ntl < 2; ntl++) {
            int nl = wn + ntl*16 + l15;
            float bv = bias_ext[384 + nl];
            float gw = g2_w[nl];
#pragma unroll
            for (int mt = 0; mt < 4; mt++)
#pragma unroll
                for (int r = 0; r < 4; r++) {
                    float h = acc[mt][ntl][r] + bv;
                    rs[mt][r] += fmaxf(h, 0.0f) * gw;
                }
        }
#pragma unroll
        for (int off = 1; off <= 8; off <<= 1)
#pragma unroll
            for (int mt = 0; mt < 4; mt++)
#pragma unroll
                for (int r = 0; r < 4; r++)
                    rs[mt][r] += __shfl_xor(rs[mt][r], off);
        if (l15 == 0) {
#pragma unroll
            for (int mt = 0; mt < 4; mt++)
#pragma unroll
                for (int r = 0; r < 4; r++)
                    gpart[(wave >> 1)*128 + wm + mt*16 + quad*4 + r] = rs[mt][r];
        }
        __syncthreads();
        if (tid < 128) {
            float g = gpart[tid] + gpart[128 + tid] + g2_b[0];
            gate[m0 + tid] = 1.0f / (1.0f + __expf(-g));
        }
    }
}

// ---------------------------------------------------------------------------
// attention: r10 byte-identical (8x8 tile x head-pair, 2 waves, lane=pixel,
// fdot2 scores, pk_fma PV, per-key register prefetch, Q/rpb hoisted).
// ---------------------------------------------------------------------------
__global__ __launch_bounds__(128) void attn_kernel(
    const unsigned short* __restrict__ qkvb, const float* __restrict__ rpb,
    unsigned short* __restrict__ attnb)
{
    __shared__ __align__(16) unsigned short kvs[196 * 136];
    __shared__ float rpb_lds[2 * 169];

    const int blk = blockIdx.x;
    const int pr = blk & 1;               // head pair
    const int tile = (blk >> 1) & 63;
    const int b = blk >> 7;
    const int ti0 = (tile >> 3) * 8, tj0 = (tile & 7) * 8;
    int wr0 = ti0 - 3; if (wr0 < 0) wr0 = 0;
    int wc0 = tj0 - 3; if (wc0 < 0) wc0 = 0;

    const int tid = threadIdx.x;
    const int hh = tid >> 6, lane = tid & 63;
    const int h = pr * 2 + hh;
    const int pi = lane >> 3, pj = lane & 7;
    const int i = ti0 + pi, j = tj0 + pj;
    int sh = i - 3; sh = sh < 0 ? 0 : (sh > 57 ? 57 : sh);
    int sw = j - 3; sw = sw < 0 ? 0 : (sw > 57 ? 57 : sw);
    const int dr = sh - wr0, dc = sw - wc0;
    const size_t gp = (size_t)(((b << 6) + i) << 6) + j;

    // --- Q load FIRST: latency overlaps the staging stream below ---
    unsigned int qu[16];
    const unsigned short* qptr = qkvb + gp * 384 + h * 32;
    *(uint4*)(qu + 0)  = *(const uint4*)(qptr + 0);
    *(uint4*)(qu + 4)  = *(const uint4*)(qptr + 8);
    *(uint4*)(qu + 8)  = *(const uint4*)(qptr + 16);
    *(uint4*)(qu + 12) = *(const uint4*)(qptr + 24);

    float rpb_v[3];
#pragma unroll
    for (int t = 0; t < 3; t++) {
        int idx = tid + t * 128;
        rpb_v[t] = (idx < 338) ? rpb[pr * 338 + idx] : 0.0f;
    }

    // stage K/V: 196 positions x 16 chunks (16B).  t<8: K dims pr*64..+63,
    // t>=8: V same slice.  dst row stride 136 hw.
    for (int idx = tid; idx < 196 * 16; idx += 128) {
        int pos = idx >> 4, t = idx & 15;
        int wr = pos / 14, wc = pos - wr * 14;
        int gr = wr0 + wr; if (gr > 63) gr = 63;
        int gc = wc0 + wc; if (gc > 63) gc = 63;
        size_t gpos = (size_t)(((b << 6) + gr) << 6) + gc;
        int src = 128 + ((t >> 3) << 7) + pr * 64 + ((t & 7) << 3);
        uint4 v = *(const uint4*)(qkvb + gpos * 384 + src);
        *(uint4*)(kvs + pos * 136 + ((t >> 3) << 6) + ((t & 7) << 3)) = v;
    }
#pragma unroll
    for (int t = 0; t < 3; t++) {
        int idx = tid + t * 128;
        if (idx < 338) rpb_lds[idx] = rpb_v[t];
    }
    __syncthreads();

    f32x2 acc2[16];
#pragma unroll
    for (int p = 0; p < 16; p++) acc2[p] = (f32x2){0.f, 0.f};
    float ssum = 0.0f;

    const float* rl = rpb_lds + hh * 169;
    const int rbase = (sh - i + 6) * 13 + (sw - j + 6);
    const int hwbase = (dr * 14 + dc) * 136 + hh * 32;

    for (int kr = 0; kr < 7; kr++) {
        const unsigned short* rowp = kvs + hwbase + kr * (14 * 136);
        const int ri = rbase + kr * 13;

        unsigned int ku[16], vu[16];
        // preload key kc=0 of this row
        *(uint4*)(ku + 0)  = *(const uint4*)(rowp + 0);
        *(uint4*)(ku + 4)  = *(const uint4*)(rowp + 8);
        *(uint4*)(ku + 8)  = *(const uint4*)(rowp + 16);
        *(uint4*)(ku + 12) = *(const uint4*)(rowp + 24);
        *(uint4*)(vu + 0)  = *(const uint4*)(rowp + 64);
        *(uint4*)(vu + 4)  = *(const uint4*)(rowp + 72);
        *(uint4*)(vu + 8)  = *(const uint4*)(rowp + 80);
        *(uint4*)(vu + 12) = *(const uint4*)(rowp + 88);

#pragma unroll
        for (int kc = 0; kc < 7; kc++) {
            unsigned int ku2[16], vu2[16];
            if (kc < 6) {   // prefetch next key while computing current
                const unsigned short* kpn = rowp + (kc + 1) * 136;
                *(uint4*)(ku2 + 0)  = *(const uint4*)(kpn + 0);
                *(uint4*)(ku2 + 4)  = *(const uint4*)(kpn + 8);
                *(uint4*)(ku2 + 8)  = *(const uint4*)(kpn + 16);
                *(uint4*)(ku2 + 12) = *(const uint4*)(kpn + 24);
                *(uint4*)(vu2 + 0)  = *(const uint4*)(kpn + 64);
                *(uint4*)(vu2 + 4)  = *(const uint4*)(kpn + 72);
                *(uint4*)(vu2 + 8)  = *(const uint4*)(kpn + 80);
                *(uint4*)(vu2 + 12) = *(const uint4*)(kpn + 88);
            }

            // scores: 4 parallel fdot2 chains (depth 4 each)
            float s0 = rl[ri + kc], s1 = 0.0f, s2 = 0.0f, s3 = 0.0f;
#if __has_builtin(__builtin_amdgcn_fdot2_f32_bf16)
#pragma unroll
            for (int p = 0; p < 4; p++) {
                s0 = __builtin_amdgcn_fdot2_f32_bf16(
                        __builtin_bit_cast(bf16x2, qu[p]),
                        __builtin_bit_cast(bf16x2, ku[p]), s0, false);
                s1 = __builtin_amdgcn_fdot2_f32_bf16(
                        __builtin_bit_cast(bf16x2, qu[p+4]),
                        __builtin_bit_cast(bf16x2, ku[p+4]), s1, false);
                s2 = __builtin_amdgcn_fdot2_f32_bf16(
                        __builtin_bit_cast(bf16x2, qu[p+8]),
                        __builtin_bit_cast(bf16x2, ku[p+8]), s2, false);
                s3 = __builtin_amdgcn_fdot2_f32_bf16(
                        __builtin_bit_cast(bf16x2, qu[p+12]),
                        __builtin_bit_cast(bf16x2, ku[p+12]), s3, false);
            }
#else
#pragma unroll
            for (int p = 0; p < 4; p++) {
                s0 += bflo(qu[p])    * bflo(ku[p])    + bfhi(qu[p])    * bfhi(ku[p]);
                s1 += bflo(qu[p+4])  * bflo(ku[p+4])  + bfhi(qu[p+4])  * bfhi(ku[p+4]);
                s2 += bflo(qu[p+8])  * bflo(ku[p+8])  + bfhi(qu[p+8])  * bfhi(ku[p+8]);
                s3 += bflo(qu[p+12]) * bflo(ku[p+12]) + bfhi(qu[p+12]) * bfhi(ku[p+12]);
            }
#endif
            float e = __expf((s0 + s1) + (s2 + s3));   // max-free: bounded scores
            ssum += e;

            // PV: packed f32x2 (v_pk_fma_f32)
            f32x2 e2 = {e, e};
#pragma unroll
            for (int p = 0; p < 16; p++) {
                f32x2 v2 = {bflo(vu[p]), bfhi(vu[p])};
                acc2[p] += e2 * v2;
            }

            if (kc < 6) {   // rotate (SSA-renamed away under full unroll)
#pragma unroll
                for (int p = 0; p < 16; p++) { ku[p] = ku2[p]; vu[p] = vu2[p]; }
            }
        }
    }

    const float inv = 1.0f / ssum;
    unsigned int o[16];
#pragma unroll
    for (int p = 0; p < 16; p++) {
        unsigned int lo = f2bf(acc2[p].x * inv);
        unsigned int hi = f2bf(acc2[p].y * inv);
        o[p] = lo | (hi << 16);
    }
    unsigned short* op = attnb + gp * 128 + h * 32;
    *(uint4*)(op + 0)  = *(const uint4*)(o + 0);
    *(uint4*)(op + 8)  = *(const uint4*)(o + 4);
    *(uint4*)(op + 16) = *(const uint4*)(o + 8);
    *(uint4*)(op + 24) = *(const uint4*)(o + 12);
}

// ---------------------------------------------------------------------------
// GEMM 2: out = (attnb @ pT^T + proj_b) * gate + x.  (unchanged)
// ---------------------------------------------------------------------------
__global__ __launch_bounds__(256) void gemm_proj_mfma(
    const unsigned short* __restrict__ ab, const unsigned short* __restrict__ pT,
    const float* __restrict__ proj_b, const float* __restrict__ gate,
    const float* __restrict__ x, float* __restrict__ out)
{
    __shared__ __align__(16) unsigned short As[64*128];
    __shared__ __align__(16) unsigned short Bs[64*128];
    const int n0 = blockIdx.x * 64;
    const int m0 = blockIdx.y * 64;
    const int tid = threadIdx.x;

#pragma unroll
    for (int it = 0; it < 4; it++) {
        int idx = tid + it*256, row = idx >> 4, c = idx & 15;
        uint4 v = *(const uint4*)(ab + (size_t)(m0+row)*128 + c*8);
        *(uint4*)(As + row*128 + ((c ^ (row&7)) << 3)) = v;
    }
#pragma unroll
    for (int it = 0; it < 4; it++) {
        int idx = tid + it*256, row = idx >> 4, c = idx & 15;
        uint4 v = *(const uint4*)(pT + (size_t)(n0+row)*128 + c*8);
        *(uint4*)(Bs + row*128 + ((c ^ (row&7)) << 3)) = v;
    }
    __syncthreads();

    const int wave = tid >> 6, lane = tid & 63;
    const int l15 = lane & 15, quad = lane >> 4;
    const int wm = (wave & 1) * 32, wn = (wave >> 1) * 32;

    f32x4 acc[2][2] = {};
#pragma unroll
    for (int ks = 0; ks < 4; ks++) {
        bf16x8 af[2], bq[2];
#pragma unroll
        for (int mt = 0; mt < 2; mt++) {
            int m = wm + mt*16 + l15;
            af[mt] = *(const bf16x8*)(As + m*128 + (((ks*4+quad) ^ (m&7)) << 3));
        }
#pragma unroll
        for (int ntl = 0; ntl < 2; ntl++) {
            int n = wn + ntl*16 + l15;
            bq[ntl] = *(const bf16x8*)(Bs + n*128 + (((ks*4+quad) ^ (n&7)) << 3));
        }
#pragma unroll
        for (int mt = 0; mt < 2; mt++)
#pragma unroll
            for (int ntl = 0; ntl < 2; ntl++)
                acc[mt][ntl] = __builtin_amdgcn_mfma_f32_16x16x32_bf16(
                    af[mt], bq[ntl], acc[mt][ntl], 0, 0, 0);
    }
    __syncthreads();

    float* Cs = (float*)As;   // 64x64 f32
#pragma unroll
    for (int ntl = 0; ntl < 2; ntl++) {
        int nl = wn + ntl*16 + l15;
        float bv = proj_b[n0 + nl];
#pragma unroll
        for (int mt = 0; mt < 2; mt++)
#pragma unroll
            for (int r = 0; r < 4; r++) {
                int ml = wm + mt*16 + quad*4 + r;
                Cs[ml*64 + nl] = acc[mt][ntl][r] + bv;
            }
    }
    __syncthreads();
    int row = tid >> 2, part = tid & 3;
    float gv = gate[m0 + row];
    const float* xr = x + (size_t)(m0+row)*128 + n0 + part*16;
    float* orow = out + (size_t)(m0+row)*128 + n0 + part*16;
#pragma unroll
    for (int q = 0; q < 4; q++) {
        float4 cv = *(const float4*)(Cs + row*64 + part*16 + q*4);
        float4 xv = *(const float4*)(xr + q*4);
        float4 o;
        o.x = cv.x * gv + xv.x; o.y = cv.y * gv + xv.y;
        o.z = cv.z * gv + xv.z; o.w = cv.w * gv + xv.w;
        *(float4*)(orow + q*4) = o;
    }
}

// ---------------------------------------------------------------------------
extern "C" void kernel_launch(void* const* d_in, const int* in_sizes, int n_in,
                              void* d_out, int out_size, void* d_ws, size_t ws_size,
                              hipStream_t stream)
{
    const float* x      = (const float*)d_in[0];
    const float* qkv_w  = (const float*)d_in[1];
    const float* qkv_b  = (const float*)d_in[2];
    const float* proj_w = (const float*)d_in[3];
    const float* proj_b = (const float*)d_in[4];
    const float* rpb    = (const float*)d_in[5];
    const float* g1_w   = (const float*)d_in[6];
    const float* g1_b   = (const float*)d_in[7];
    const float* g2_w   = (const float*)d_in[8];
    const float* g2_b   = (const float*)d_in[9];
    float* out = (float*)d_out;

    float* ws        = (float*)d_ws;
    float* gate      = ws;                          // 16384 f32
    float* bias_ext  = gate + 16384;                // 448 f32
    unsigned short* wT    = (unsigned short*)(bias_ext + 448);  // 448*128
    unsigned short* pT    = wT + 57344;             // 128*128
    unsigned short* qkvb  = pT + 16384;             // 16384*384 bf16
    unsigned short* attnb = qkvb + 6291456;         // 16384*128 bf16

    (void)in_sizes; (void)n_in; (void)out_size; (void)ws_size;

    prep_kernel<<<73, 256, 0, stream>>>(qkv_w, g1_w, qkv_b, g1_b, proj_w,
                                        wT, pT, bias_ext);
    gemm_qkvh_fused<<<dim3(7, 128), 256, 0, stream>>>(x, wT, bias_ext,
                                                      g2_w, g2_b, qkvb, gate);
    attn_kernel<<<512, 128, 0, stream>>>(qkvb, rpb, attnb);
    gemm_proj_mfma<<<dim3(2, 256), 256, 0, stream>>>(attnb, pT, proj_b, gate, x, out);
}

// Round 12
// 115.940 us; speedup vs baseline: 1.0370x; 1.0370x over previous
//
#include <hip/hip_runtime.h>
#include <hip/hip_bf16.h>
#include <math.h>

#define PIXELS 16384   // 4*64*64
#define C      128
#define KS     7
#define HEADS  4
#define HD     32      // head dim
#define QSCALE 0.17677669529663687f  // 32^-0.5

typedef __bf16 bf16x8 __attribute__((ext_vector_type(8)));
typedef __bf16 bf16x2 __attribute__((ext_vector_type(2)));
typedef float  f32x4  __attribute__((ext_vector_type(4)));
typedef float  f32x2  __attribute__((ext_vector_type(2)));

__device__ inline unsigned short f2bf(float f) {
    unsigned int u = __builtin_bit_cast(unsigned int, f);
    u += 0x7FFFu + ((u >> 16) & 1u);          // RNE
    return (unsigned short)(u >> 16);
}
__device__ inline float bflo(unsigned int u) {
    return __builtin_bit_cast(float, u << 16);
}
__device__ inline float bfhi(unsigned int u) {
    return __builtin_bit_cast(float, u & 0xFFFF0000u);
}

// ---------------------------------------------------------------------------
// prep (weights only): wT[448][128] = [qkv_w|g1_w]^T bf16;
// pT[128][128] = proj_w^T bf16; bias_ext[448].  grid 73 x 256.  (unchanged)
// ---------------------------------------------------------------------------
__global__ __launch_bounds__(256) void prep_kernel(
    const float* __restrict__ qkv_w, const float* __restrict__ g1_w,
    const float* __restrict__ qkv_b, const float* __restrict__ g1_b,
    const float* __restrict__ proj_w,
    unsigned short* __restrict__ wT, unsigned short* __restrict__ pT,
    float* __restrict__ bias_ext)
{
    const int blk = blockIdx.x, tid = threadIdx.x;
    if (blk < 56) {
        int n = blk * 8 + (tid >> 5);
        int kq = tid & 31;
        float f0, f1, f2, f3;
        if (n < 384) {
            f0 = qkv_w[(kq*4+0)*384 + n]; f1 = qkv_w[(kq*4+1)*384 + n];
            f2 = qkv_w[(kq*4+2)*384 + n]; f3 = qkv_w[(kq*4+3)*384 + n];
        } else {
            int nn = n - 384;
            f0 = g1_w[(kq*4+0)*64 + nn]; f1 = g1_w[(kq*4+1)*64 + nn];
            f2 = g1_w[(kq*4+2)*64 + nn]; f3 = g1_w[(kq*4+3)*64 + nn];
        }
        ushort4 o; o.x = f2bf(f0); o.y = f2bf(f1); o.z = f2bf(f2); o.w = f2bf(f3);
        *(ushort4*)(wT + n*128 + kq*4) = o;
    } else if (blk < 72) {
        int n = (blk - 56) * 8 + (tid >> 5);
        int kq = tid & 31;
        ushort4 o;
        o.x = f2bf(proj_w[(kq*4+0)*128 + n]);
        o.y = f2bf(proj_w[(kq*4+1)*128 + n]);
        o.z = f2bf(proj_w[(kq*4+2)*128 + n]);
        o.w = f2bf(proj_w[(kq*4+3)*128 + n]);
        *(ushort4*)(pT + n*128 + kq*4) = o;
    } else {
        for (int idx = tid; idx < 448; idx += 256)
            bias_ext[idx] = (idx < 384) ? qkv_b[idx] : g1_b[idx - 384];
    }
}

// ---------------------------------------------------------------------------
// GEMM 1 (fused): qkvb[pix][384] bf16 = bf16(x @ W + b), q cols scaled.
// N-TILE LOOP: block stages its 64x128 A tile ONCE (fp32->bf16) and loops
// over N-tiles (grp 0: nt 0..3, grp 1: nt 4..6 incl. gate).  x HBM reads
// 56 -> 16 MB; A-staging instructions / 3.5.  LDS 40 KB (As16+Bs16+Cs8)
// -> 2 blocks/CU, 8 waves/CU.  grid (2, 256) x 256.
// ---------------------------------------------------------------------------
__global__ __launch_bounds__(256) void gemm_qkvh_fused(
    const float* __restrict__ x, const unsigned short* __restrict__ wT,
    const float* __restrict__ bias_ext, const float* __restrict__ g2_w,
    const float* __restrict__ g2_b, unsigned short* __restrict__ qkvb,
    float* __restrict__ gate)
{
    __shared__ __align__(16) unsigned short As[64*128];   // 16 KB, persists
    __shared__ __align__(16) unsigned short Bs[64*128];   // 16 KB, per tile
    __shared__ __align__(16) unsigned short Cs[64*64];    // 8 KB epilogue / gate
    const int grp = blockIdx.x;
    const int ntBeg = grp ? 4 : 0, ntEnd = grp ? 7 : 4;
    const int m0 = blockIdx.y * 64;
    const int tid = threadIdx.x;

    // stage A once: 64 rows x 16 chunks, fp32->bf16 during LDS write
#pragma unroll
    for (int it = 0; it < 4; it++) {
        int idx = tid + it*256, row = idx >> 4, c = idx & 15;
        const float* src = x + (size_t)(m0+row)*128 + c*8;
        float4 a = *(const float4*)src;
        float4 b2 = *(const float4*)(src + 4);
        uint4 v;
        v.x = (unsigned int)f2bf(a.x)  | ((unsigned int)f2bf(a.y)  << 16);
        v.y = (unsigned int)f2bf(a.z)  | ((unsigned int)f2bf(a.w)  << 16);
        v.z = (unsigned int)f2bf(b2.x) | ((unsigned int)f2bf(b2.y) << 16);
        v.w = (unsigned int)f2bf(b2.z) | ((unsigned int)f2bf(b2.w) << 16);
        *(uint4*)(As + row*128 + ((c ^ (row&7)) << 3)) = v;
    }

    const int wave = tid >> 6, lane = tid & 63;
    const int l15 = lane & 15, quad = lane >> 4;
    const int wm = (wave & 1) * 32, wn = (wave >> 1) * 32;

    for (int nt = ntBeg; nt < ntEnd; nt++) {
        const int n0 = nt * 64;
        // stage B tile (prev iter's sync2 guarantees Bs readers are done)
#pragma unroll
        for (int it = 0; it < 4; it++) {
            int idx = tid + it*256, row = idx >> 4, c = idx & 15;
            uint4 v = *(const uint4*)(wT + (size_t)(n0+row)*128 + c*8);
            *(uint4*)(Bs + row*128 + ((c ^ (row&7)) << 3)) = v;
        }
        __syncthreads();   // sync1: B (and first-iter A) visible; prev Cs reads done

        f32x4 acc[2][2] = {};
#pragma unroll
        for (int ks = 0; ks < 4; ks++) {
            bf16x8 af[2], bq[2];
#pragma unroll
            for (int mt = 0; mt < 2; mt++) {
                int m = wm + mt*16 + l15;
                af[mt] = *(const bf16x8*)(As + m*128 + (((ks*4+quad) ^ (m&7)) << 3));
            }
#pragma unroll
            for (int ntl = 0; ntl < 2; ntl++) {
                int n = wn + ntl*16 + l15;
                bq[ntl] = *(const bf16x8*)(Bs + n*128 + (((ks*4+quad) ^ (n&7)) << 3));
            }
#pragma unroll
            for (int mt = 0; mt < 2; mt++)
#pragma unroll
                for (int ntl = 0; ntl < 2; ntl++)
                    acc[mt][ntl] = __builtin_amdgcn_mfma_f32_16x16x32_bf16(
                        af[mt], bq[ntl], acc[mt][ntl], 0, 0, 0);
        }

        if (nt < 6) {
            // C layout: col=lane&15, row=quad*4+r.  LDS roundtrip via Cs.
#pragma unroll
            for (int ntl = 0; ntl < 2; ntl++) {
                int nl = wn + ntl*16 + l15;
                int ng = n0 + nl;
                float qs = (ng < 128) ? QSCALE : 1.0f;
                float bv = bias_ext[ng];
#pragma unroll
                for (int mt = 0; mt < 2; mt++)
#pragma unroll
                    for (int r = 0; r < 4; r++) {
                        int ml = wm + mt*16 + quad*4 + r;
                        Cs[ml*64 + nl] = f2bf((acc[mt][ntl][r] + bv) * qs);
                    }
            }
            __syncthreads();   // sync2: Cs complete; also guards Bs restage
            int row = tid >> 2, part = tid & 3;
            uint4 a = *(const uint4*)(Cs + row*64 + part*16);
            uint4 b = *(const uint4*)(Cs + row*64 + part*16 + 8);
            unsigned short* dst = qkvb + (size_t)(m0+row)*384 + n0 + part*16;
            *(uint4*)dst = a;
            *(uint4*)(dst + 8) = b;
        } else {
            // gate: sum over 64 hidden cols of relu(h)*g2w, sigmoid.
            float* gpart = (float*)Cs;   // [2][64] f32
            float rs[2][4];
#pragma unroll
            for (int mt = 0; mt < 2; mt++)
#pragma unroll
                for (int r = 0; r < 4; r++) rs[mt][r] = 0.0f;
#pragma unroll
            for (int ntl = 0; ntl < 2; ntl++) {
                int nl = wn + ntl*16 + l15;
                float bv = bias_ext[384 + nl];
                float gw = g2_w[nl];
#pragma unroll
                for (int mt = 0; mt < 2; mt++)
#pragma unroll
                    for (int r = 0; r < 4; r++) {
                        float h = acc[mt][ntl][r] + bv;
                        rs[mt][r] += fmaxf(h, 0.0f) * gw;
                    }
            }
#pragma unroll
            for (int off = 1; off <= 8; off <<= 1)
#pragma unroll
                for (int mt = 0; mt < 2; mt++)
#pragma unroll
                    for (int r = 0; r < 4; r++)
                        rs[mt][r] += __shfl_xor(rs[mt][r], off);
            if (l15 == 0) {
#pragma unroll
                for (int mt = 0; mt < 2; mt++)
#pragma unroll
                    for (int r = 0; r < 4; r++)
                        gpart[(wave >> 1)*64 + wm + mt*16 + quad*4 + r] = rs[mt][r];
            }
            __syncthreads();
            if (tid < 64) {
                float g = gpart[tid] + gpart[64 + tid] + g2_b[0];
                gate[m0 + tid] = 1.0f / (1.0f + __expf(-g));
            }
        }
    }
}

// ---------------------------------------------------------------------------
// attention: r10 byte-identical (8x8 tile x head-pair, 2 waves, lane=pixel,
// fdot2 scores, pk_fma PV, per-key register prefetch, Q/rpb hoisted).
// ---------------------------------------------------------------------------
__global__ __launch_bounds__(128) void attn_kernel(
    const unsigned short* __restrict__ qkvb, const float* __restrict__ rpb,
    unsigned short* __restrict__ attnb)
{
    __shared__ __align__(16) unsigned short kvs[196 * 136];
    __shared__ float rpb_lds[2 * 169];

    const int blk = blockIdx.x;
    const int pr = blk & 1;               // head pair
    const int tile = (blk >> 1) & 63;
    const int b = blk >> 7;
    const int ti0 = (tile >> 3) * 8, tj0 = (tile & 7) * 8;
    int wr0 = ti0 - 3; if (wr0 < 0) wr0 = 0;
    int wc0 = tj0 - 3; if (wc0 < 0) wc0 = 0;

    const int tid = threadIdx.x;
    const int hh = tid >> 6, lane = tid & 63;
    const int h = pr * 2 + hh;
    const int pi = lane >> 3, pj = lane & 7;
    const int i = ti0 + pi, j = tj0 + pj;
    int sh = i - 3; sh = sh < 0 ? 0 : (sh > 57 ? 57 : sh);
    int sw = j - 3; sw = sw < 0 ? 0 : (sw > 57 ? 57 : sw);
    const int dr = sh - wr0, dc = sw - wc0;
    const size_t gp = (size_t)(((b << 6) + i) << 6) + j;

    // --- Q load FIRST: latency overlaps the staging stream below ---
    unsigned int qu[16];
    const unsigned short* qptr = qkvb + gp * 384 + h * 32;
    *(uint4*)(qu + 0)  = *(const uint4*)(qptr + 0);
    *(uint4*)(qu + 4)  = *(const uint4*)(qptr + 8);
    *(uint4*)(qu + 8)  = *(const uint4*)(qptr + 16);
    *(uint4*)(qu + 12) = *(const uint4*)(qptr + 24);

    float rpb_v[3];
#pragma unroll
    for (int t = 0; t < 3; t++) {
        int idx = tid + t * 128;
        rpb_v[t] = (idx < 338) ? rpb[pr * 338 + idx] : 0.0f;
    }

    // stage K/V: 196 positions x 16 chunks (16B).  t<8: K dims pr*64..+63,
    // t>=8: V same slice.  dst row stride 136 hw.
    for (int idx = tid; idx < 196 * 16; idx += 128) {
        int pos = idx >> 4, t = idx & 15;
        int wr = pos / 14, wc = pos - wr * 14;
        int gr = wr0 + wr; if (gr > 63) gr = 63;
        int gc = wc0 + wc; if (gc > 63) gc = 63;
        size_t gpos = (size_t)(((b << 6) + gr) << 6) + gc;
        int src = 128 + ((t >> 3) << 7) + pr * 64 + ((t & 7) << 3);
        uint4 v = *(const uint4*)(qkvb + gpos * 384 + src);
        *(uint4*)(kvs + pos * 136 + ((t >> 3) << 6) + ((t & 7) << 3)) = v;
    }
#pragma unroll
    for (int t = 0; t < 3; t++) {
        int idx = tid + t * 128;
        if (idx < 338) rpb_lds[idx] = rpb_v[t];
    }
    __syncthreads();

    f32x2 acc2[16];
#pragma unroll
    for (int p = 0; p < 16; p++) acc2[p] = (f32x2){0.f, 0.f};
    float ssum = 0.0f;

    const float* rl = rpb_lds + hh * 169;
    const int rbase = (sh - i + 6) * 13 + (sw - j + 6);
    const int hwbase = (dr * 14 + dc) * 136 + hh * 32;

    for (int kr = 0; kr < 7; kr++) {
        const unsigned short* rowp = kvs + hwbase + kr * (14 * 136);
        const int ri = rbase + kr * 13;

        unsigned int ku[16], vu[16];
        // preload key kc=0 of this row
        *(uint4*)(ku + 0)  = *(const uint4*)(rowp + 0);
        *(uint4*)(ku + 4)  = *(const uint4*)(rowp + 8);
        *(uint4*)(ku + 8)  = *(const uint4*)(rowp + 16);
        *(uint4*)(ku + 12) = *(const uint4*)(rowp + 24);
        *(uint4*)(vu + 0)  = *(const uint4*)(rowp + 64);
        *(uint4*)(vu + 4)  = *(const uint4*)(rowp + 72);
        *(uint4*)(vu + 8)  = *(const uint4*)(rowp + 80);
        *(uint4*)(vu + 12) = *(const uint4*)(rowp + 88);

#pragma unroll
        for (int kc = 0; kc < 7; kc++) {
            unsigned int ku2[16], vu2[16];
            if (kc < 6) {   // prefetch next key while computing current
                const unsigned short* kpn = rowp + (kc + 1) * 136;
                *(uint4*)(ku2 + 0)  = *(const uint4*)(kpn + 0);
                *(uint4*)(ku2 + 4)  = *(const uint4*)(kpn + 8);
                *(uint4*)(ku2 + 8)  = *(const uint4*)(kpn + 16);
                *(uint4*)(ku2 + 12) = *(const uint4*)(kpn + 24);
                *(uint4*)(vu2 + 0)  = *(const uint4*)(kpn + 64);
                *(uint4*)(vu2 + 4)  = *(const uint4*)(kpn + 72);
                *(uint4*)(vu2 + 8)  = *(const uint4*)(kpn + 80);
                *(uint4*)(vu2 + 12) = *(const uint4*)(kpn + 88);
            }

            // scores: 4 parallel fdot2 chains (depth 4 each)
            float s0 = rl[ri + kc], s1 = 0.0f, s2 = 0.0f, s3 = 0.0f;
#if __has_builtin(__builtin_amdgcn_fdot2_f32_bf16)
#pragma unroll
            for (int p = 0; p < 4; p++) {
                s0 = __builtin_amdgcn_fdot2_f32_bf16(
                        __builtin_bit_cast(bf16x2, qu[p]),
                        __builtin_bit_cast(bf16x2, ku[p]), s0, false);
                s1 = __builtin_amdgcn_fdot2_f32_bf16(
                        __builtin_bit_cast(bf16x2, qu[p+4]),
                        __builtin_bit_cast(bf16x2, ku[p+4]), s1, false);
                s2 = __builtin_amdgcn_fdot2_f32_bf16(
                        __builtin_bit_cast(bf16x2, qu[p+8]),
                        __builtin_bit_cast(bf16x2, ku[p+8]), s2, false);
                s3 = __builtin_amdgcn_fdot2_f32_bf16(
                        __builtin_bit_cast(bf16x2, qu[p+12]),
                        __builtin_bit_cast(bf16x2, ku[p+12]), s3, false);
            }
#else
#pragma unroll
            for (int p = 0; p < 4; p++) {
                s0 += bflo(qu[p])    * bflo(ku[p])    + bfhi(qu[p])    * bfhi(ku[p]);
                s1 += bflo(qu[p+4])  * bflo(ku[p+4])  + bfhi(qu[p+4])  * bfhi(ku[p+4]);
                s2 += bflo(qu[p+8])  * bflo(ku[p+8])  + bfhi(qu[p+8])  * bfhi(ku[p+8]);
                s3 += bflo(qu[p+12]) * bflo(ku[p+12]) + bfhi(qu[p+12]) * bfhi(ku[p+12]);
            }
#endif
            float e = __expf((s0 + s1) + (s2 + s3));   // max-free: bounded scores
            ssum += e;

            // PV: packed f32x2 (v_pk_fma_f32)
            f32x2 e2 = {e, e};
#pragma unroll
            for (int p = 0; p < 16; p++) {
                f32x2 v2 = {bflo(vu[p]), bfhi(vu[p])};
                acc2[p] += e2 * v2;
            }

            if (kc < 6) {   // rotate (SSA-renamed away under full unroll)
#pragma unroll
                for (int p = 0; p < 16; p++) { ku[p] = ku2[p]; vu[p] = vu2[p]; }
            }
        }
    }

    const float inv = 1.0f / ssum;
    unsigned int o[16];
#pragma unroll
    for (int p = 0; p < 16; p++) {
        unsigned int lo = f2bf(acc2[p].x * inv);
        unsigned int hi = f2bf(acc2[p].y * inv);
        o[p] = lo | (hi << 16);
    }
    unsigned short* op = attnb + gp * 128 + h * 32;
    *(uint4*)(op + 0)  = *(const uint4*)(o + 0);
    *(uint4*)(op + 8)  = *(const uint4*)(o + 4);
    *(uint4*)(op + 16) = *(const uint4*)(o + 8);
    *(uint4*)(op + 24) = *(const uint4*)(o + 12);
}

// ---------------------------------------------------------------------------
// GEMM 2: out = (attnb @ pT^T + proj_b) * gate + x.  (unchanged)
// ---------------------------------------------------------------------------
__global__ __launch_bounds__(256) void gemm_proj_mfma(
    const unsigned short* __restrict__ ab, const unsigned short* __restrict__ pT,
    const float* __restrict__ proj_b, const float* __restrict__ gate,
    const float* __restrict__ x, float* __restrict__ out)
{
    __shared__ __align__(16) unsigned short As[64*128];
    __shared__ __align__(16) unsigned short Bs[64*128];
    const int n0 = blockIdx.x * 64;
    const int m0 = blockIdx.y * 64;
    const int tid = threadIdx.x;

#pragma unroll
    for (int it = 0; it < 4; it++) {
        int idx = tid + it*256, row = idx >> 4, c = idx & 15;
        uint4 v = *(const uint4*)(ab + (size_t)(m0+row)*128 + c*8);
        *(uint4*)(As + row*128 + ((c ^ (row&7)) << 3)) = v;
    }
#pragma unroll
    for (int it = 0; it < 4; it++) {
        int idx = tid + it*256, row = idx >> 4, c = idx & 15;
        uint4 v = *(const uint4*)(pT + (size_t)(n0+row)*128 + c*8);
        *(uint4*)(Bs + row*128 + ((c ^ (row&7)) << 3)) = v;
    }
    __syncthreads();

    const int wave = tid >> 6, lane = tid & 63;
    const int l15 = lane & 15, quad = lane >> 4;
    const int wm = (wave & 1) * 32, wn = (wave >> 1) * 32;

    f32x4 acc[2][2] = {};
#pragma unroll
    for (int ks = 0; ks < 4; ks++) {
        bf16x8 af[2], bq[2];
#pragma unroll
        for (int mt = 0; mt < 2; mt++) {
            int m = wm + mt*16 + l15;
            af[mt] = *(const bf16x8*)(As + m*128 + (((ks*4+quad) ^ (m&7)) << 3));
        }
#pragma unroll
        for (int ntl = 0; ntl < 2; ntl++) {
            int n = wn + ntl*16 + l15;
            bq[ntl] = *(const bf16x8*)(Bs + n*128 + (((ks*4+quad) ^ (n&7)) << 3));
        }
#pragma unroll
        for (int mt = 0; mt < 2; mt++)
#pragma unroll
            for (int ntl = 0; ntl < 2; ntl++)
                acc[mt][ntl] = __builtin_amdgcn_mfma_f32_16x16x32_bf16(
                    af[mt], bq[ntl], acc[mt][ntl], 0, 0, 0);
    }
    __syncthreads();

    float* Cs = (float*)As;   // 64x64 f32
#pragma unroll
    for (int ntl = 0; ntl < 2; ntl++) {
        int nl = wn + ntl*16 + l15;
        float bv = proj_b[n0 + nl];
#pragma unroll
        for (int mt = 0; mt < 2; mt++)
#pragma unroll
            for (int r = 0; r < 4; r++) {
                int ml = wm + mt*16 + quad*4 + r;
                Cs[ml*64 + nl] = acc[mt][ntl][r] + bv;
            }
    }
    __syncthreads();
    int row = tid >> 2, part = tid & 3;
    float gv = gate[m0 + row];
    const float* xr = x + (size_t)(m0+row)*128 + n0 + part*16;
    float* orow = out + (size_t)(m0+row)*128 + n0 + part*16;
#pragma unroll
    for (int q = 0; q < 4; q++) {
        float4 cv = *(const float4*)(Cs + row*64 + part*16 + q*4);
        float4 xv = *(const float4*)(xr + q*4);
        float4 o;
        o.x = cv.x * gv + xv.x; o.y = cv.y * gv + xv.y;
        o.z = cv.z * gv + xv.z; o.w = cv.w * gv + xv.w;
        *(float4*)(orow + q*4) = o;
    }
}

// ---------------------------------------------------------------------------
extern "C" void kernel_launch(void* const* d_in, const int* in_sizes, int n_in,
                              void* d_out, int out_size, void* d_ws, size_t ws_size,
                              hipStream_t stream)
{
    const float* x      = (const float*)d_in[0];
    const float* qkv_w  = (const float*)d_in[1];
    const float* qkv_b  = (const float*)d_in[2];
    const float* proj_w = (const float*)d_in[3];
    const float* proj_b = (const float*)d_in[4];
    const float* rpb    = (const float*)d_in[5];
    const float* g1_w   = (const float*)d_in[6];
    const float* g1_b   = (const float*)d_in[7];
    const float* g2_w   = (const float*)d_in[8];
    const float* g2_b   = (const float*)d_in[9];
    float* out = (float*)d_out;

    float* ws        = (float*)d_ws;
    float* gate      = ws;                          // 16384 f32
    float* bias_ext  = gate + 16384;                // 448 f32
    unsigned short* wT    = (unsigned short*)(bias_ext + 448);  // 448*128
    unsigned short* pT    = wT + 57344;             // 128*128
    unsigned short* qkvb  = pT + 16384;             // 16384*384 bf16
    unsigned short* attnb = qkvb + 6291456;         // 16384*128 bf16

    (void)in_sizes; (void)n_in; (void)out_size; (void)ws_size;

    prep_kernel<<<73, 256, 0, stream>>>(qkv_w, g1_w, qkv_b, g1_b, proj_w,
                                        wT, pT, bias_ext);
    gemm_qkvh_fused<<<dim3(2, 256), 256, 0, stream>>>(x, wT, bias_ext,
                                                      g2_w, g2_b, qkvb, gate);
    attn_kernel<<<512, 128, 0, stream>>>(qkvb, rpb, attnb);
    gemm_proj_mfma<<<dim3(2, 256), 256, 0, stream>>>(attnb, pT, proj_b, gate, x, out);
}

// Round 13
// 115.775 us; speedup vs baseline: 1.0385x; 1.0014x over previous
//
#include <hip/hip_runtime.h>
#include <hip/hip_bf16.h>
#include <math.h>

#define PIXELS 16384   // 4*64*64
#define C      128
#define KS     7
#define HEADS  4
#define HD     32      // head dim
#define QSCALE 0.17677669529663687f  // 32^-0.5

typedef __bf16 bf16x8 __attribute__((ext_vector_type(8)));
typedef __bf16 bf16x2 __attribute__((ext_vector_type(2)));
typedef float  f32x4  __attribute__((ext_vector_type(4)));
typedef float  f32x2  __attribute__((ext_vector_type(2)));

__device__ inline unsigned short f2bf(float f) {
    unsigned int u = __builtin_bit_cast(unsigned int, f);
    u += 0x7FFFu + ((u >> 16) & 1u);          // RNE
    return (unsigned short)(u >> 16);
}
__device__ inline float bflo(unsigned int u) {
    return __builtin_bit_cast(float, u << 16);
}
__device__ inline float bfhi(unsigned int u) {
    return __builtin_bit_cast(float, u & 0xFFFF0000u);
}

// ---------------------------------------------------------------------------
// prep (weights only): wT[448][128] = [qkv_w|g1_w]^T bf16;
// pT[128][128] = proj_w^T bf16; bias_ext[448].  grid 73 x 256.  (unchanged)
// ---------------------------------------------------------------------------
__global__ __launch_bounds__(256) void prep_kernel(
    const float* __restrict__ qkv_w, const float* __restrict__ g1_w,
    const float* __restrict__ qkv_b, const float* __restrict__ g1_b,
    const float* __restrict__ proj_w,
    unsigned short* __restrict__ wT, unsigned short* __restrict__ pT,
    float* __restrict__ bias_ext)
{
    const int blk = blockIdx.x, tid = threadIdx.x;
    if (blk < 56) {
        int n = blk * 8 + (tid >> 5);
        int kq = tid & 31;
        float f0, f1, f2, f3;
        if (n < 384) {
            f0 = qkv_w[(kq*4+0)*384 + n]; f1 = qkv_w[(kq*4+1)*384 + n];
            f2 = qkv_w[(kq*4+2)*384 + n]; f3 = qkv_w[(kq*4+3)*384 + n];
        } else {
            int nn = n - 384;
            f0 = g1_w[(kq*4+0)*64 + nn]; f1 = g1_w[(kq*4+1)*64 + nn];
            f2 = g1_w[(kq*4+2)*64 + nn]; f3 = g1_w[(kq*4+3)*64 + nn];
        }
        ushort4 o; o.x = f2bf(f0); o.y = f2bf(f1); o.z = f2bf(f2); o.w = f2bf(f3);
        *(ushort4*)(wT + n*128 + kq*4) = o;
    } else if (blk < 72) {
        int n = (blk - 56) * 8 + (tid >> 5);
        int kq = tid & 31;
        ushort4 o;
        o.x = f2bf(proj_w[(kq*4+0)*128 + n]);
        o.y = f2bf(proj_w[(kq*4+1)*128 + n]);
        o.z = f2bf(proj_w[(kq*4+2)*128 + n]);
        o.w = f2bf(proj_w[(kq*4+3)*128 + n]);
        *(ushort4*)(pT + n*128 + kq*4) = o;
    } else {
        for (int idx = tid; idx < 448; idx += 256)
            bias_ext[idx] = (idx < 384) ? qkv_b[idx] : g1_b[idx - 384];
    }
}

// ---------------------------------------------------------------------------
// GEMM 1 (fused): qkvb[pix][384] bf16, N-tile loop, gate fused.  (r12,
// unchanged)
// ---------------------------------------------------------------------------
__global__ __launch_bounds__(256) void gemm_qkvh_fused(
    const float* __restrict__ x, const unsigned short* __restrict__ wT,
    const float* __restrict__ bias_ext, const float* __restrict__ g2_w,
    const float* __restrict__ g2_b, unsigned short* __restrict__ qkvb,
    float* __restrict__ gate)
{
    __shared__ __align__(16) unsigned short As[64*128];   // 16 KB, persists
    __shared__ __align__(16) unsigned short Bs[64*128];   // 16 KB, per tile
    __shared__ __align__(16) unsigned short Cs[64*64];    // 8 KB epilogue / gate
    const int grp = blockIdx.x;
    const int ntBeg = grp ? 4 : 0, ntEnd = grp ? 7 : 4;
    const int m0 = blockIdx.y * 64;
    const int tid = threadIdx.x;

#pragma unroll
    for (int it = 0; it < 4; it++) {
        int idx = tid + it*256, row = idx >> 4, c = idx & 15;
        const float* src = x + (size_t)(m0+row)*128 + c*8;
        float4 a = *(const float4*)src;
        float4 b2 = *(const float4*)(src + 4);
        uint4 v;
        v.x = (unsigned int)f2bf(a.x)  | ((unsigned int)f2bf(a.y)  << 16);
        v.y = (unsigned int)f2bf(a.z)  | ((unsigned int)f2bf(a.w)  << 16);
        v.z = (unsigned int)f2bf(b2.x) | ((unsigned int)f2bf(b2.y) << 16);
        v.w = (unsigned int)f2bf(b2.z) | ((unsigned int)f2bf(b2.w) << 16);
        *(uint4*)(As + row*128 + ((c ^ (row&7)) << 3)) = v;
    }

    const int wave = tid >> 6, lane = tid & 63;
    const int l15 = lane & 15, quad = lane >> 4;
    const int wm = (wave & 1) * 32, wn = (wave >> 1) * 32;

    for (int nt = ntBeg; nt < ntEnd; nt++) {
        const int n0 = nt * 64;
#pragma unroll
        for (int it = 0; it < 4; it++) {
            int idx = tid + it*256, row = idx >> 4, c = idx & 15;
            uint4 v = *(const uint4*)(wT + (size_t)(n0+row)*128 + c*8);
            *(uint4*)(Bs + row*128 + ((c ^ (row&7)) << 3)) = v;
        }
        __syncthreads();   // sync1

        f32x4 acc[2][2] = {};
#pragma unroll
        for (int ks = 0; ks < 4; ks++) {
            bf16x8 af[2], bq[2];
#pragma unroll
            for (int mt = 0; mt < 2; mt++) {
                int m = wm + mt*16 + l15;
                af[mt] = *(const bf16x8*)(As + m*128 + (((ks*4+quad) ^ (m&7)) << 3));
            }
#pragma unroll
            for (int ntl = 0; ntl < 2; ntl++) {
                int n = wn + ntl*16 + l15;
                bq[ntl] = *(const bf16x8*)(Bs + n*128 + (((ks*4+quad) ^ (n&7)) << 3));
            }
#pragma unroll
            for (int mt = 0; mt < 2; mt++)
#pragma unroll
                for (int ntl = 0; ntl < 2; ntl++)
                    acc[mt][ntl] = __builtin_amdgcn_mfma_f32_16x16x32_bf16(
                        af[mt], bq[ntl], acc[mt][ntl], 0, 0, 0);
        }

        if (nt < 6) {
#pragma unroll
            for (int ntl = 0; ntl < 2; ntl++) {
                int nl = wn + ntl*16 + l15;
                int ng = n0 + nl;
                float qs = (ng < 128) ? QSCALE : 1.0f;
                float bv = bias_ext[ng];
#pragma unroll
                for (int mt = 0; mt < 2; mt++)
#pragma unroll
                    for (int r = 0; r < 4; r++) {
                        int ml = wm + mt*16 + quad*4 + r;
                        Cs[ml*64 + nl] = f2bf((acc[mt][ntl][r] + bv) * qs);
                    }
            }
            __syncthreads();   // sync2
            int row = tid >> 2, part = tid & 3;
            uint4 a = *(const uint4*)(Cs + row*64 + part*16);
            uint4 b = *(const uint4*)(Cs + row*64 + part*16 + 8);
            unsigned short* dst = qkvb + (size_t)(m0+row)*384 + n0 + part*16;
            *(uint4*)dst = a;
            *(uint4*)(dst + 8) = b;
        } else {
            float* gpart = (float*)Cs;   // [2][64] f32
            float rs[2][4];
#pragma unroll
            for (int mt = 0; mt < 2; mt++)
#pragma unroll
                for (int r = 0; r < 4; r++) rs[mt][r] = 0.0f;
#pragma unroll
            for (int ntl = 0; ntl < 2; ntl++) {
                int nl = wn + ntl*16 + l15;
                float bv = bias_ext[384 + nl];
                float gw = g2_w[nl];
#pragma unroll
                for (int mt = 0; mt < 2; mt++)
#pragma unroll
                    for (int r = 0; r < 4; r++) {
                        float h = acc[mt][ntl][r] + bv;
                        rs[mt][r] += fmaxf(h, 0.0f) * gw;
                    }
            }
#pragma unroll
            for (int off = 1; off <= 8; off <<= 1)
#pragma unroll
                for (int mt = 0; mt < 2; mt++)
#pragma unroll
                    for (int r = 0; r < 4; r++)
                        rs[mt][r] += __shfl_xor(rs[mt][r], off);
            if (l15 == 0) {
#pragma unroll
                for (int mt = 0; mt < 2; mt++)
#pragma unroll
                    for (int r = 0; r < 4; r++)
                        gpart[(wave >> 1)*64 + wm + mt*16 + quad*4 + r] = rs[mt][r];
            }
            __syncthreads();
            if (tid < 64) {
                float g = gpart[tid] + gpart[64 + tid] + g2_b[0];
                gate[m0 + tid] = 1.0f / (1.0f + __expf(-g));
            }
        }
    }
}

// ---------------------------------------------------------------------------
// attention v3: block = (batch, 4x8 tile, head-pair), 128 thr = 2 waves
// (wave = head).  lane = (pixel, dim-half): 32 pixels x 2 halves, each lane
// owns 16 dims -> private 49-key loop + ONE shfl_xor(32) per key to
// complete the score (bias added post-shuffle; both halves then identical).
// Head-pairing keeps full 256 B K/V lines (r8 lesson); no inter-wave
// coupling (r6 lesson).  Window 10x14 = 140 pos, LDS 38.5 KB -> 4 blocks/CU
// x 2 waves = 8 waves/CU (2x r12's latency hiding).  grid 1024 x 128.
// ---------------------------------------------------------------------------
__global__ __launch_bounds__(128) void attn_kernel(
    const unsigned short* __restrict__ qkvb, const float* __restrict__ rpb,
    unsigned short* __restrict__ attnb)
{
    __shared__ __align__(16) unsigned short kvs[140 * 136];
    __shared__ float rpb_lds[2 * 169];

    const int blk = blockIdx.x;
    const int pr = blk & 1;               // head pair
    const int tile = (blk >> 1) & 127;    // 16 row-tiles x 8 col-tiles
    const int b = blk >> 8;
    const int ti0 = (tile >> 3) * 4, tj0 = (tile & 7) * 8;
    int wr0 = ti0 - 3; wr0 = wr0 < 0 ? 0 : (wr0 > 54 ? 54 : wr0);
    int wc0 = tj0 - 3; wc0 = wc0 < 0 ? 0 : (wc0 > 50 ? 50 : wc0);

    const int tid = threadIdx.x;
    const int hh = tid >> 6, lane = tid & 63;
    const int h = pr * 2 + hh;
    const int half = lane >> 5;           // dim half: 0 = dims 0..15, 1 = 16..31
    const int p5 = lane & 31;
    const int pi = p5 >> 3, pj = p5 & 7;
    const int i = ti0 + pi, j = tj0 + pj;
    int sh = i - 3; sh = sh < 0 ? 0 : (sh > 57 ? 57 : sh);
    int sw = j - 3; sw = sw < 0 ? 0 : (sw > 57 ? 57 : sw);
    const int dr = sh - wr0, dc = sw - wc0;
    const size_t gp = (size_t)(((b << 6) + i) << 6) + j;

    // --- Q (this half's 16 dims) FIRST: latency hides under staging ---
    unsigned int qu[8];
    const unsigned short* qptr = qkvb + gp * 384 + h * 32 + half * 16;
    *(uint4*)(qu + 0) = *(const uint4*)(qptr + 0);
    *(uint4*)(qu + 4) = *(const uint4*)(qptr + 8);

    float rpb_v[3];
#pragma unroll
    for (int t = 0; t < 3; t++) {
        int idx = tid + t * 128;
        rpb_v[t] = (idx < 338) ? rpb[pr * 338 + idx] : 0.0f;
    }

    // stage K/V: 140 pos x 16 chunks (16B).  Window fits interior: no clamp.
    // row layout: [K h0(32) | K h1(32) | V h0(32) | V h1(32) | pad(8)] hw.
    for (int idx = tid; idx < 140 * 16; idx += 128) {
        int pos = idx >> 4, t = idx & 15;
        int wr = pos / 14, wc = pos - wr * 14;
        size_t gpos = (size_t)(((b << 6) + (wr0 + wr)) << 6) + (wc0 + wc);
        int src = 128 + ((t >> 3) << 7) + pr * 64 + ((t & 7) << 3);
        uint4 v = *(const uint4*)(qkvb + gpos * 384 + src);
        *(uint4*)(kvs + pos * 136 + ((t >> 3) << 6) + ((t & 7) << 3)) = v;
    }
#pragma unroll
    for (int t = 0; t < 3; t++) {
        int idx = tid + t * 128;
        if (idx < 338) rpb_lds[idx] = rpb_v[t];
    }
    __syncthreads();

    f32x2 acc2[8];
#pragma unroll
    for (int p = 0; p < 8; p++) acc2[p] = (f32x2){0.f, 0.f};
    float ssum = 0.0f;

    const float* rl = rpb_lds + hh * 169;
    const int rbase = (sh - i + 6) * 13 + (sw - j + 6);
    const int hwbase = (dr * 14 + dc) * 136 + hh * 32 + half * 16;

    for (int kr = 0; kr < 7; kr++) {
        const unsigned short* rowp = kvs + hwbase + kr * (14 * 136);
        const int ri = rbase + kr * 13;

        unsigned int ku[8], vu[8];
        *(uint4*)(ku + 0) = *(const uint4*)(rowp + 0);
        *(uint4*)(ku + 4) = *(const uint4*)(rowp + 8);
        *(uint4*)(vu + 0) = *(const uint4*)(rowp + 64);
        *(uint4*)(vu + 4) = *(const uint4*)(rowp + 72);

#pragma unroll
        for (int kc = 0; kc < 7; kc++) {
            unsigned int ku2[8], vu2[8];
            if (kc < 6) {   // prefetch next key while computing current
                const unsigned short* kpn = rowp + (kc + 1) * 136;
                *(uint4*)(ku2 + 0) = *(const uint4*)(kpn + 0);
                *(uint4*)(ku2 + 4) = *(const uint4*)(kpn + 8);
                *(uint4*)(vu2 + 0) = *(const uint4*)(kpn + 64);
                *(uint4*)(vu2 + 4) = *(const uint4*)(kpn + 72);
            }

            // partial score over this half's 16 dims: 2 fdot2 chains of 4
            float s0 = 0.0f, s1 = 0.0f;
#if __has_builtin(__builtin_amdgcn_fdot2_f32_bf16)
#pragma unroll
            for (int p = 0; p < 4; p++) {
                s0 = __builtin_amdgcn_fdot2_f32_bf16(
                        __builtin_bit_cast(bf16x2, qu[p]),
                        __builtin_bit_cast(bf16x2, ku[p]), s0, false);
                s1 = __builtin_amdgcn_fdot2_f32_bf16(
                        __builtin_bit_cast(bf16x2, qu[p+4]),
                        __builtin_bit_cast(bf16x2, ku[p+4]), s1, false);
            }
#else
#pragma unroll
            for (int p = 0; p < 4; p++) {
                s0 += bflo(qu[p])   * bflo(ku[p])   + bfhi(qu[p])   * bfhi(ku[p]);
                s1 += bflo(qu[p+4]) * bflo(ku[p+4]) + bfhi(qu[p+4]) * bfhi(ku[p+4]);
            }
#endif
            float s = s0 + s1;
            s += __shfl_xor(s, 32);          // combine the two dim-halves
            float e = __expf(s + rl[ri + kc]);  // max-free: bounded scores
            ssum += e;                        // both halves identical

            // PV for this half's 16 dims: 8 pk_fma
            f32x2 e2 = {e, e};
#pragma unroll
            for (int p = 0; p < 8; p++) {
                f32x2 v2 = {bflo(vu[p]), bfhi(vu[p])};
                acc2[p] += e2 * v2;
            }

            if (kc < 6) {
#pragma unroll
                for (int p = 0; p < 8; p++) { ku[p] = ku2[p]; vu[p] = vu2[p]; }
            }
        }
    }

    const float inv = 1.0f / ssum;
    unsigned int o[8];
#pragma unroll
    for (int p = 0; p < 8; p++) {
        unsigned int lo = f2bf(acc2[p].x * inv);
        unsigned int hi = f2bf(acc2[p].y * inv);
        o[p] = lo | (hi << 16);
    }
    unsigned short* op = attnb + gp * 128 + h * 32 + half * 16;
    *(uint4*)(op + 0) = *(const uint4*)(o + 0);
    *(uint4*)(op + 8) = *(const uint4*)(o + 4);
}

// ---------------------------------------------------------------------------
// GEMM 2: out = (attnb @ pT^T + proj_b) * gate + x.  (unchanged)
// ---------------------------------------------------------------------------
__global__ __launch_bounds__(256) void gemm_proj_mfma(
    const unsigned short* __restrict__ ab, const unsigned short* __restrict__ pT,
    const float* __restrict__ proj_b, const float* __restrict__ gate,
    const float* __restrict__ x, float* __restrict__ out)
{
    __shared__ __align__(16) unsigned short As[64*128];
    __shared__ __align__(16) unsigned short Bs[64*128];
    const int n0 = blockIdx.x * 64;
    const int m0 = blockIdx.y * 64;
    const int tid = threadIdx.x;

#pragma unroll
    for (int it = 0; it < 4; it++) {
        int idx = tid + it*256, row = idx >> 4, c = idx & 15;
        uint4 v = *(const uint4*)(ab + (size_t)(m0+row)*128 + c*8);
        *(uint4*)(As + row*128 + ((c ^ (row&7)) << 3)) = v;
    }
#pragma unroll
    for (int it = 0; it < 4; it++) {
        int idx = tid + it*256, row = idx >> 4, c = idx & 15;
        uint4 v = *(const uint4*)(pT + (size_t)(n0+row)*128 + c*8);
        *(uint4*)(Bs + row*128 + ((c ^ (row&7)) << 3)) = v;
    }
    __syncthreads();

    const int wave = tid >> 6, lane = tid & 63;
    const int l15 = lane & 15, quad = lane >> 4;
    const int wm = (wave & 1) * 32, wn = (wave >> 1) * 32;

    f32x4 acc[2][2] = {};
#pragma unroll
    for (int ks = 0; ks < 4; ks++) {
        bf16x8 af[2], bq[2];
#pragma unroll
        for (int mt = 0; mt < 2; mt++) {
            int m = wm + mt*16 + l15;
            af[mt] = *(const bf16x8*)(As + m*128 + (((ks*4+quad) ^ (m&7)) << 3));
        }
#pragma unroll
        for (int ntl = 0; ntl < 2; ntl++) {
            int n = wn + ntl*16 + l15;
            bq[ntl] = *(const bf16x8*)(Bs + n*128 + (((ks*4+quad) ^ (n&7)) << 3));
        }
#pragma unroll
        for (int mt = 0; mt < 2; mt++)
#pragma unroll
            for (int ntl = 0; ntl < 2; ntl++)
                acc[mt][ntl] = __builtin_amdgcn_mfma_f32_16x16x32_bf16(
                    af[mt], bq[ntl], acc[mt][ntl], 0, 0, 0);
    }
    __syncthreads();

    float* Cs = (float*)As;   // 64x64 f32
#pragma unroll
    for (int ntl = 0; ntl < 2; ntl++) {
        int nl = wn + ntl*16 + l15;
        float bv = proj_b[n0 + nl];
#pragma unroll
        for (int mt = 0; mt < 2; mt++)
#pragma unroll
            for (int r = 0; r < 4; r++) {
                int ml = wm + mt*16 + quad*4 + r;
                Cs[ml*64 + nl] = acc[mt][ntl][r] + bv;
            }
    }
    __syncthreads();
    int row = tid >> 2, part = tid & 3;
    float gv = gate[m0 + row];
    const float* xr = x + (size_t)(m0+row)*128 + n0 + part*16;
    float* orow = out + (size_t)(m0+row)*128 + n0 + part*16;
#pragma unroll
    for (int q = 0; q < 4; q++) {
        float4 cv = *(const float4*)(Cs + row*64 + part*16 + q*4);
        float4 xv = *(const float4*)(xr + q*4);
        float4 o;
        o.x = cv.x * gv + xv.x; o.y = cv.y * gv + xv.y;
        o.z = cv.z * gv + xv.z; o.w = cv.w * gv + xv.w;
        *(float4*)(orow + q*4) = o;
    }
}

// ---------------------------------------------------------------------------
extern "C" void kernel_launch(void* const* d_in, const int* in_sizes, int n_in,
                              void* d_out, int out_size, void* d_ws, size_t ws_size,
                              hipStream_t stream)
{
    const float* x      = (const float*)d_in[0];
    const float* qkv_w  = (const float*)d_in[1];
    const float* qkv_b  = (const float*)d_in[2];
    const float* proj_w = (const float*)d_in[3];
    const float* proj_b = (const float*)d_in[4];
    const float* rpb    = (const float*)d_in[5];
    const float* g1_w   = (const float*)d_in[6];
    const float* g1_b   = (const float*)d_in[7];
    const float* g2_w   = (const float*)d_in[8];
    const float* g2_b   = (const float*)d_in[9];
    float* out = (float*)d_out;

    float* ws        = (float*)d_ws;
    float* gate      = ws;                          // 16384 f32
    float* bias_ext  = gate + 16384;                // 448 f32
    unsigned short* wT    = (unsigned short*)(bias_ext + 448);  // 448*128
    unsigned short* pT    = wT + 57344;             // 128*128
    unsigned short* qkvb  = pT + 16384;             // 16384*384 bf16
    unsigned short* attnb = qkvb + 6291456;         // 16384*128 bf16

    (void)in_sizes; (void)n_in; (void)out_size; (void)ws_size;

    prep_kernel<<<73, 256, 0, stream>>>(qkv_w, g1_w, qkv_b, g1_b, proj_w,
                                        wT, pT, bias_ext);
    gemm_qkvh_fused<<<dim3(2, 256), 256, 0, stream>>>(x, wT, bias_ext,
                                                      g2_w, g2_b, qkvb, gate);
    attn_kernel<<<1024, 128, 0, stream>>>(qkvb, rpb, attnb);
    gemm_proj_mfma<<<dim3(2, 256), 256, 0, stream>>>(attnb, pT, proj_b, gate, x, out);
}